// Round 1
// baseline (113.698 us; speedup 1.0000x reference)
//
#include <hip/hip_runtime.h>
#include <math.h>

// One block per image (B*P = 512 images, 64x64x3 fp32 each).
// Lane = column, wave = 16-row strip, sliding 3x3 window down the column.
// LDS holds a flat copy of the image (48 KB): addresses within a window-read
// instruction are 3*w + const across lanes -> gcd(3,32)=1 -> conflict-free
// (2-way aliasing is free on gfx950).

#define NW 12288   // floats per image = 64*64*3

extern "C" __global__ __launch_bounds__(256, 2)
void denoise_sharpen(const float* __restrict__ images,
                     const float* __restrict__ params,
                     const float* __restrict__ kin,
                     float* __restrict__ out)
{
    __shared__ __align__(16) float img[NW];
    __shared__ float red[9];

    const int blk = blockIdx.x;
    const int tid = threadIdx.x;
    const float* src = images + (size_t)blk * NW;
    float*       dst = out    + (size_t)blk * NW;

    // ---- stage image into LDS (coalesced float4 loads) ----
    #pragma unroll
    for (int i = 0; i < 12; ++i) {
        const int idx = i * 1024 + tid * 4;
        const float4 v = *(const float4*)(src + idx);
        *(float4*)(&img[idx]) = v;
    }

    // ---- per-image params (wave-uniform; mostly SGPR) ----
    const float* p = params + blk * 7;
    const float sigma_s = fminf(fmaxf(p[0], 0.2f), 5.0f);
    const float sigma_r = fminf(fmaxf(p[1], 0.01f), 1.0f);
    const float sigma_f = fminf(fmaxf(p[2], 0.2f), 3.0f);
    const float lam     = fminf(fmaxf(p[3], 0.1f), 2.0f);
    const float tau     = fminf(fmaxf(p[4], 0.5f), 5.0f);
    const float gain    = fminf(fmaxf(p[5], 0.2f), 2.0f);
    const float offset  = fminf(fmaxf(p[6], 0.01f), 1.0f);
    const float kpos    = fmaxf(fabsf(kin[0]), 1.0f);
    const float inv2s2  = -0.5f / (sigma_r * sigma_r);
    const float inv_tau = 1.0f / tau;

    // 1D gaussians over [-1,0,1]: [e,1,e]/(1+2e)
    const float es  = __expf(-0.5f / (sigma_s * sigma_s));
    const float gsc = 1.0f / (1.0f + 2.0f * es);
    const float gse = es * gsc;
    const float ef  = __expf(-0.5f / (sigma_f * sigma_f));
    const float gfcn = 1.0f / (1.0f + 2.0f * ef);
    const float gfe  = ef * gfcn;

    float sk[9], gk[9];
    {
        const float gsv[3] = {gse, gsc, gse};
        const float gfv[3] = {gfe, gfcn, gfe};
        #pragma unroll
        for (int i = 0; i < 3; ++i)
            #pragma unroll
            for (int j = 0; j < 3; ++j) {
                sk[i*3+j] = gsv[i] * gsv[j];
                gk[i*3+j] = gfv[i] * gfv[j];
            }
    }

    __syncthreads();

    const int w  = tid & 63;        // column = lane
    const int q  = tid >> 6;        // wave id -> row strip
    const int r0 = q << 4;          // first row of strip
    const int wl = (w == 0)  ? 1  : w - 1;   // reflect
    const int wr = (w == 63) ? 62 : w + 1;   // reflect

    float win[3][9];   // [row slot][col(l,c,r) x ch] sliding window

    auto load_row = [&](int r, float (&d)[9]) {
        const int rr = (r < 0) ? -r : ((r > 63) ? 126 - r : r);  // reflect
        const int b  = rr * 192;
        d[0] = img[b + wl*3 + 0];
        d[1] = img[b + wl*3 + 1];
        d[2] = img[b + wl*3 + 2];
        d[3] = img[b + w*3  + 0];
        d[4] = img[b + w*3  + 1];
        d[5] = img[b + w*3  + 2];
        d[6] = img[b + wr*3 + 0];
        d[7] = img[b + wr*3 + 1];
        d[8] = img[b + wr*3 + 2];
    };

    load_row(r0 - 1, win[0]);
    load_row(r0,     win[1]);

    float res[16][3];
    float s_ne = 0.0f, s_ad = 0.0f;

    #pragma unroll
    for (int s = 0; s < 16; ++s) {
        load_row(r0 + s + 1, win[(s + 2) % 3]);
        const float (&rm)[9] = win[s % 3];        // row r-1
        const float (&rc)[9] = win[(s + 1) % 3];  // row r
        const float (&rp)[9] = win[(s + 2) % 3];  // row r+1
        const float x0 = rc[3], x1 = rc[4], x2 = rc[5];

        float num0 = 0.f, num1 = 0.f, num2 = 0.f, den = 0.f;
        float gf0 = 0.f, gf1 = 0.f, gf2 = 0.f;

        const float* rows[3] = { rm, rc, rp };
        #pragma unroll
        for (int i = 0; i < 3; ++i) {
            #pragma unroll
            for (int j = 0; j < 3; ++j) {
                const float u0 = rows[i][j*3+0];
                const float u1 = rows[i][j*3+1];
                const float u2 = rows[i][j*3+2];
                const float d0 = u0 - x0, d1 = u1 - x1, d2 = u2 - x2;
                const float dist = d0*d0 + d1*d1 + d2*d2;
                const float ck = __expf(inv2s2 * dist);
                const float kr = sk[i*3+j] * ck;
                den  += kr;
                num0 += kr * u0;
                num1 += kr * u1;
                num2 += kr * u2;
                const float gw = gk[i*3+j];
                gf0 += gw * u0;
                gf1 += gw * u1;
                gf2 += gw * u2;
            }
        }
        const float invden = 1.0f / den;

        auto epi = [&](float xc, float bfc, float gfv) -> float {
            const float detail = xc - gfv;
            const float ad = fabsf(detail);
            const float ne = fminf(ad * gain / fmaxf(xc + offset, 1e-5f), 10.0f);
            s_ad += ad;
            s_ne += ne;
            const float z  = ne * inv_tau;
            const float ei = fmaxf(-z * z, -88.0f);
            const float em = 1.0f - __expf(ei);
            const float nm = em * em;
            const float dm = 1.0f / (1.0f + __expf(-kpos * (ad - 0.002f)));
            return bfc + lam * detail * nm * dm;
        };
        res[s][0] = epi(x0, num0 * invden, gf0);
        res[s][1] = epi(x1, num1 * invden, gf1);
        res[s][2] = epi(x2, num2 * invden, gf2);
    }

    // ---- block reduction for should_skip ----
    #pragma unroll
    for (int off = 32; off > 0; off >>= 1) {
        s_ne += __shfl_down(s_ne, off, 64);
        s_ad += __shfl_down(s_ad, off, 64);
    }
    if ((tid & 63) == 0) { red[2*q] = s_ne; red[2*q + 1] = s_ad; }
    __syncthreads();
    if (tid == 0) {
        const float tn = red[0] + red[2] + red[4] + red[6];
        const float ta = red[1] + red[3] + red[5] + red[7];
        const float avg_n = tn * (1.0f / 12288.0f);
        const float avg_d = ta * (1.0f / 12288.0f);
        red[8] = (avg_n < 1e-4f || avg_d < 1e-4f) ? 1.0f : 0.0f;
    }
    __syncthreads();
    const bool skip = (red[8] != 0.0f);

    // ---- finalize in-place in LDS (each thread touches only its own pixels) ----
    #pragma unroll
    for (int s = 0; s < 16; ++s) {
        const int b = ((r0 + s) * 64 + w) * 3;
        #pragma unroll
        for (int c = 0; c < 3; ++c) {
            float v = skip ? img[b + c] : res[s][c];
            v = fminf(fmaxf(v, 1e-5f), 1.0f);
            img[b + c] = v;
        }
    }
    __syncthreads();

    // ---- coalesced float4 writeback ----
    #pragma unroll
    for (int i = 0; i < 12; ++i) {
        const int idx = i * 1024 + tid * 4;
        *(float4*)(dst + idx) = *(const float4*)(&img[idx]);
    }
}

extern "C" void kernel_launch(void* const* d_in, const int* in_sizes, int n_in,
                              void* d_out, int out_size, void* d_ws, size_t ws_size,
                              hipStream_t stream) {
    const float* images = (const float*)d_in[0];
    const float* params = (const float*)d_in[1];
    const float* k      = (const float*)d_in[2];
    float* out = (float*)d_out;

    const int n_img = in_sizes[0] / NW;   // 512
    denoise_sharpen<<<dim3(n_img), dim3(256), 0, stream>>>(images, params, k, out);
}

// Round 2
// 106.868 us; speedup vs baseline: 1.0639x; 1.0639x over previous
//
#include <hip/hip_runtime.h>
#include <math.h>

// One block per image (B*P = 512 images, 64x64x3 fp32 each).
// 512 threads/block = 8 waves: lane = column, wave = 8-row strip, sliding
// 3x3 window down the column. Grid 512 x 8 waves with VGPR<=128 gives
// 2 blocks/CU -> the whole grid is co-resident (4096 of 8192 wave slots),
// vs 25% cap of the 256-thread version.
// LDS flat image copy: window reads are 3*w + const across lanes ->
// gcd(3,32)=1 -> only free 2-way aliasing, no bank conflicts.

#define NW 12288   // floats per image = 64*64*3

extern "C" __global__ __launch_bounds__(512, 4)
void denoise_sharpen(const float* __restrict__ images,
                     const float* __restrict__ params,
                     const float* __restrict__ kin,
                     float* __restrict__ out)
{
    __shared__ __align__(16) float img[NW];
    __shared__ float red[17];

    const int blk = blockIdx.x;
    const int tid = threadIdx.x;
    const float* src = images + (size_t)blk * NW;
    float*       dst = out    + (size_t)blk * NW;

    // ---- stage image into LDS (coalesced float4 loads) ----
    #pragma unroll
    for (int i = 0; i < 6; ++i) {
        const int idx = i * 2048 + tid * 4;
        const float4 v = *(const float4*)(src + idx);
        *(float4*)(&img[idx]) = v;
    }

    // ---- per-image params (block-uniform) ----
    const float* p = params + blk * 7;
    const float sigma_s = fminf(fmaxf(p[0], 0.2f), 5.0f);
    const float sigma_r = fminf(fmaxf(p[1], 0.01f), 1.0f);
    const float sigma_f = fminf(fmaxf(p[2], 0.2f), 3.0f);
    const float lam     = fminf(fmaxf(p[3], 0.1f), 2.0f);
    const float tau     = fminf(fmaxf(p[4], 0.5f), 5.0f);
    const float gain    = fminf(fmaxf(p[5], 0.2f), 2.0f);
    const float offset  = fminf(fmaxf(p[6], 0.01f), 1.0f);
    const float kpos    = fmaxf(fabsf(kin[0]), 1.0f);
    const float inv2s2  = -0.5f / (sigma_r * sigma_r);
    const float inv_tau = 1.0f / tau;

    // 1D gaussians over [-1,0,1]: [e,1,e]/(1+2e)
    const float es  = __expf(-0.5f / (sigma_s * sigma_s));
    const float gsc = 1.0f / (1.0f + 2.0f * es);
    const float gse = es * gsc;
    const float ef  = __expf(-0.5f / (sigma_f * sigma_f));
    const float gfcn = 1.0f / (1.0f + 2.0f * ef);
    const float gfe  = ef * gfcn;

    float sk[9], gk[9];
    {
        const float gsv[3] = {gse, gsc, gse};
        const float gfv[3] = {gfe, gfcn, gfe};
        #pragma unroll
        for (int i = 0; i < 3; ++i)
            #pragma unroll
            for (int j = 0; j < 3; ++j) {
                sk[i*3+j] = gsv[i] * gsv[j];
                gk[i*3+j] = gfv[i] * gfv[j];
            }
    }

    __syncthreads();

    const int w  = tid & 63;        // column = lane
    const int q  = tid >> 6;        // wave id -> 8-row strip
    const int r0 = q << 3;          // first row of strip
    const int wl = (w == 0)  ? 1  : w - 1;   // reflect
    const int wr = (w == 63) ? 62 : w + 1;   // reflect

    float win[3][9];   // [row slot][col(l,c,r) x ch] sliding window

    auto load_row = [&](int r, float (&d)[9]) {
        const int rr = (r < 0) ? -r : ((r > 63) ? 126 - r : r);  // reflect
        const int b  = rr * 192;
        d[0] = img[b + wl*3 + 0];
        d[1] = img[b + wl*3 + 1];
        d[2] = img[b + wl*3 + 2];
        d[3] = img[b + w*3  + 0];
        d[4] = img[b + w*3  + 1];
        d[5] = img[b + w*3  + 2];
        d[6] = img[b + wr*3 + 0];
        d[7] = img[b + wr*3 + 1];
        d[8] = img[b + wr*3 + 2];
    };

    load_row(r0 - 1, win[0]);
    load_row(r0,     win[1]);

    float res[8][3];
    float s_ne = 0.0f, s_ad = 0.0f;

    #pragma unroll
    for (int s = 0; s < 8; ++s) {
        load_row(r0 + s + 1, win[(s + 2) % 3]);
        const float (&rm)[9] = win[s % 3];        // row r-1
        const float (&rc)[9] = win[(s + 1) % 3];  // row r
        const float (&rp)[9] = win[(s + 2) % 3];  // row r+1
        const float x0 = rc[3], x1 = rc[4], x2 = rc[5];

        float num0 = 0.f, num1 = 0.f, num2 = 0.f, den = 0.f;
        float gf0 = 0.f, gf1 = 0.f, gf2 = 0.f;

        const float* rows[3] = { rm, rc, rp };
        #pragma unroll
        for (int i = 0; i < 3; ++i) {
            #pragma unroll
            for (int j = 0; j < 3; ++j) {
                const float u0 = rows[i][j*3+0];
                const float u1 = rows[i][j*3+1];
                const float u2 = rows[i][j*3+2];
                const float d0 = u0 - x0, d1 = u1 - x1, d2 = u2 - x2;
                const float dist = d0*d0 + d1*d1 + d2*d2;
                const float ck = __expf(inv2s2 * dist);
                const float kr = sk[i*3+j] * ck;
                den  += kr;
                num0 += kr * u0;
                num1 += kr * u1;
                num2 += kr * u2;
                const float gw = gk[i*3+j];
                gf0 += gw * u0;
                gf1 += gw * u1;
                gf2 += gw * u2;
            }
        }
        const float invden = __builtin_amdgcn_rcpf(den);  // den >= center weight > 0

        auto epi = [&](float xc, float bfc, float gfv) -> float {
            const float detail = xc - gfv;
            const float ad = fabsf(detail);
            const float ne = fminf(ad * gain * __builtin_amdgcn_rcpf(fmaxf(xc + offset, 1e-5f)), 10.0f);
            s_ad += ad;
            s_ne += ne;
            const float z  = ne * inv_tau;
            const float ei = fmaxf(-z * z, -88.0f);
            const float em = 1.0f - __expf(ei);
            const float nm = em * em;
            const float dm = __builtin_amdgcn_rcpf(1.0f + __expf(-kpos * (ad - 0.002f)));
            return bfc + lam * detail * nm * dm;
        };
        res[s][0] = epi(x0, num0 * invden, gf0);
        res[s][1] = epi(x1, num1 * invden, gf1);
        res[s][2] = epi(x2, num2 * invden, gf2);
    }

    // ---- block reduction for should_skip ----
    #pragma unroll
    for (int off = 32; off > 0; off >>= 1) {
        s_ne += __shfl_down(s_ne, off, 64);
        s_ad += __shfl_down(s_ad, off, 64);
    }
    if ((tid & 63) == 0) { red[2*q] = s_ne; red[2*q + 1] = s_ad; }
    __syncthreads();
    if (tid == 0) {
        float tn = 0.f, ta = 0.f;
        #pragma unroll
        for (int i = 0; i < 8; ++i) { tn += red[2*i]; ta += red[2*i+1]; }
        const float avg_n = tn * (1.0f / 12288.0f);
        const float avg_d = ta * (1.0f / 12288.0f);
        red[16] = (avg_n < 1e-4f || avg_d < 1e-4f) ? 1.0f : 0.0f;
    }
    __syncthreads();
    const bool skip = (red[16] != 0.0f);

    // ---- finalize straight to global (lane w writes 12 contiguous bytes
    //      at base + 12*w -> fully coalesced 768B per wave-row) ----
    #pragma unroll
    for (int s = 0; s < 8; ++s) {
        const int b = ((r0 + s) * 64 + w) * 3;
        #pragma unroll
        for (int c = 0; c < 3; ++c) {
            float v = skip ? img[b + c] : res[s][c];
            v = fminf(fmaxf(v, 1e-5f), 1.0f);
            dst[b + c] = v;
        }
    }
}

extern "C" void kernel_launch(void* const* d_in, const int* in_sizes, int n_in,
                              void* d_out, int out_size, void* d_ws, size_t ws_size,
                              hipStream_t stream) {
    const float* images = (const float*)d_in[0];
    const float* params = (const float*)d_in[1];
    const float* k      = (const float*)d_in[2];
    float* out = (float*)d_out;

    const int n_img = in_sizes[0] / NW;   // 512
    denoise_sharpen<<<dim3(n_img), dim3(512), 0, stream>>>(images, params, k, out);
}

// Round 3
// 95.411 us; speedup vs baseline: 1.1917x; 1.1201x over previous
//
#include <hip/hip_runtime.h>
#include <math.h>

// One block per image (512 images, 64x64x3 fp32). 512 thr = 8 waves;
// lane = column, wave = 8-row strip, sliding 3x3 window down the column.
// R3: scratch-ectomy. No res[][] (results stored to global immediately;
// rare skip-images rewritten from the LDS copy after the reduction),
// no pointer arrays, window rotation fully explicit -> everything stays
// in VGPRs (~55 live floats).

#define NW 12288   // floats per image = 64*64*3

extern "C" __global__ __launch_bounds__(512, 4)
void denoise_sharpen(const float* __restrict__ images,
                     const float* __restrict__ params,
                     const float* __restrict__ kin,
                     float* __restrict__ out)
{
    __shared__ __align__(16) float img[NW];
    __shared__ float red[17];

    const int blk = blockIdx.x;
    const int tid = threadIdx.x;
    const float* src = images + (size_t)blk * NW;
    float*       dst = out    + (size_t)blk * NW;

    // ---- stage image into LDS (coalesced float4) ----
    #pragma unroll
    for (int i = 0; i < 6; ++i) {
        const int idx = i * 2048 + tid * 4;
        *(float4*)(&img[idx]) = *(const float4*)(src + idx);
    }

    // ---- per-image params (blockIdx-indexed -> scalar loads / SGPRs) ----
    const float* p = params + blk * 7;
    const float sigma_s = fminf(fmaxf(p[0], 0.2f), 5.0f);
    const float sigma_r = fminf(fmaxf(p[1], 0.01f), 1.0f);
    const float sigma_f = fminf(fmaxf(p[2], 0.2f), 3.0f);
    const float lam     = fminf(fmaxf(p[3], 0.1f), 2.0f);
    const float tau     = fminf(fmaxf(p[4], 0.5f), 5.0f);
    const float gain    = fminf(fmaxf(p[5], 0.2f), 2.0f);
    const float offset  = fminf(fmaxf(p[6], 0.01f), 1.0f);
    const float kpos    = fmaxf(fabsf(kin[0]), 1.0f);
    const float inv2s2  = -0.5f / (sigma_r * sigma_r);
    const float inv_tau = 1.0f / tau;

    // 1D gaussians over [-1,0,1]: [e,1,e]/(1+2e) -- 4 uniform scalars total
    const float es   = __expf(-0.5f / (sigma_s * sigma_s));
    const float gsc  = 1.0f / (1.0f + 2.0f * es);
    const float gse  = es * gsc;
    const float ef   = __expf(-0.5f / (sigma_f * sigma_f));
    const float gfc  = 1.0f / (1.0f + 2.0f * ef);
    const float gfe  = ef * gfc;

    __syncthreads();

    const int w  = tid & 63;        // column = lane
    const int q  = tid >> 6;        // wave id -> 8-row strip
    const int r0 = q << 3;
    const int wl = (w == 0)  ? 1  : w - 1;   // reflect
    const int wr = (w == 63) ? 62 : w + 1;   // reflect

    float s_ne = 0.0f, s_ad = 0.0f;

    auto load_row = [&](int r, float (&d)[9]) {
        const int rr = (r < 0) ? -r : ((r > 63) ? 126 - r : r);  // reflect
        const int b  = rr * 192;
        d[0] = img[b + wl*3 + 0];
        d[1] = img[b + wl*3 + 1];
        d[2] = img[b + wl*3 + 2];
        d[3] = img[b + w*3  + 0];
        d[4] = img[b + w*3  + 1];
        d[5] = img[b + w*3  + 2];
        d[6] = img[b + wr*3 + 0];
        d[7] = img[b + wr*3 + 1];
        d[8] = img[b + wr*3 + 2];
    };

    auto epi = [&](float xc, float bfc, float gfv) -> float {
        const float detail = xc - gfv;
        const float ad = fabsf(detail);
        const float ne = fminf(ad * gain * __builtin_amdgcn_rcpf(fmaxf(xc + offset, 1e-5f)), 10.0f);
        s_ad += ad;
        s_ne += ne;
        const float z  = ne * inv_tau;
        const float ei = fmaxf(-z * z, -88.0f);
        const float em = 1.0f - __expf(ei);
        const float nm = em * em;
        const float dm = __builtin_amdgcn_rcpf(1.0f + __expf(-kpos * (ad - 0.002f)));
        const float v  = bfc + lam * detail * nm * dm;
        return fminf(fmaxf(v, 1e-5f), 1.0f);
    };

    // one window row's contribution; all indices compile-time constant
    auto acc_row = [&](const float (&rw)[9], float vs, float vf,
                       float x0, float x1, float x2,
                       float& den, float& n0, float& n1, float& n2,
                       float& g0, float& g1, float& g2) {
        #pragma unroll
        for (int j = 0; j < 3; ++j) {
            const float hs = (j == 1) ? gsc : gse;
            const float hf = (j == 1) ? gfc : gfe;
            const float u0 = rw[j*3+0], u1 = rw[j*3+1], u2 = rw[j*3+2];
            const float d0 = u0 - x0, d1 = u1 - x1, d2 = u2 - x2;
            const float dist = d0*d0 + d1*d1 + d2*d2;
            const float ck = __expf(inv2s2 * dist);
            const float kr = (vs * hs) * ck;
            den += kr;
            n0 += kr * u0; n1 += kr * u1; n2 += kr * u2;
            const float gw = vf * hf;
            g0 += gw * u0; g1 += gw * u1; g2 += gw * u2;
        }
    };

    // process row r0+s: rm/rc current window, load next into rp
    auto step = [&](float (&rm)[9], float (&rc)[9], float (&rp)[9], int s) {
        load_row(r0 + s + 1, rp);
        const float x0 = rc[3], x1 = rc[4], x2 = rc[5];
        float den = 0.f, n0 = 0.f, n1 = 0.f, n2 = 0.f;
        float g0 = 0.f, g1 = 0.f, g2 = 0.f;
        acc_row(rm, gse, gfe, x0, x1, x2, den, n0, n1, n2, g0, g1, g2);
        acc_row(rc, gsc, gfc, x0, x1, x2, den, n0, n1, n2, g0, g1, g2);
        acc_row(rp, gse, gfe, x0, x1, x2, den, n0, n1, n2, g0, g1, g2);
        const float invden = __builtin_amdgcn_rcpf(den);  // den >= gsc^2 > 0
        const int b = ((r0 + s) * 64 + w) * 3;
        dst[b + 0] = epi(x0, n0 * invden, g0);
        dst[b + 1] = epi(x1, n1 * invden, g1);
        dst[b + 2] = epi(x2, n2 * invden, g2);
    };

    float wa[9], wb[9], wc[9];
    load_row(r0 - 1, wa);
    load_row(r0,     wb);
    step(wa, wb, wc, 0);
    step(wb, wc, wa, 1);
    step(wc, wa, wb, 2);
    step(wa, wb, wc, 3);
    step(wb, wc, wa, 4);
    step(wc, wa, wb, 5);
    step(wa, wb, wc, 6);
    step(wb, wc, wa, 7);

    // ---- should_skip reduction ----
    #pragma unroll
    for (int off = 32; off > 0; off >>= 1) {
        s_ne += __shfl_down(s_ne, off, 64);
        s_ad += __shfl_down(s_ad, off, 64);
    }
    if ((tid & 63) == 0) { red[2*q] = s_ne; red[2*q + 1] = s_ad; }
    __syncthreads();
    if (tid == 0) {
        float tn = 0.f, ta = 0.f;
        #pragma unroll
        for (int i = 0; i < 8; ++i) { tn += red[2*i]; ta += red[2*i+1]; }
        red[16] = (tn * (1.0f/12288.0f) < 1e-4f || ta * (1.0f/12288.0f) < 1e-4f) ? 1.0f : 0.0f;
    }
    __syncthreads();

    // rare path: skip-image -> overwrite dst with clip(x) from LDS copy.
    // WAW with the step() stores is ordered by the barrier's vmcnt drain.
    if (red[16] != 0.0f) {
        #pragma unroll
        for (int i = 0; i < 6; ++i) {
            const int idx = i * 2048 + tid * 4;
            float4 v = *(const float4*)(&img[idx]);
            v.x = fminf(fmaxf(v.x, 1e-5f), 1.0f);
            v.y = fminf(fmaxf(v.y, 1e-5f), 1.0f);
            v.z = fminf(fmaxf(v.z, 1e-5f), 1.0f);
            v.w = fminf(fmaxf(v.w, 1e-5f), 1.0f);
            *(float4*)(dst + idx) = v;
        }
    }
}

extern "C" void kernel_launch(void* const* d_in, const int* in_sizes, int n_in,
                              void* d_out, int out_size, void* d_ws, size_t ws_size,
                              hipStream_t stream) {
    const float* images = (const float*)d_in[0];
    const float* params = (const float*)d_in[1];
    const float* k      = (const float*)d_in[2];
    float* out = (float*)d_out;

    const int n_img = in_sizes[0] / NW;   // 512
    denoise_sharpen<<<dim3(n_img), dim3(512), 0, stream>>>(images, params, k, out);
}